// Round 3
// baseline (297.981 us; speedup 1.0000x reference)
//
#include <hip/hip_runtime.h>

// (B,N,D,K) = (32, 2048, 512, 256)
#define CB 32
#define CN 2048
#define CD 512
#define CK 256

typedef __bf16 bf16x8 __attribute__((ext_vector_type(8)));
typedef float  f32x4  __attribute__((ext_vector_type(4)));

__device__ __forceinline__ unsigned pk2bf(float a, float b) {   // RNE pack: 2 f32 -> bf16x2
    union { float f; unsigned u; } x, y; x.f = a; y.f = b;
    unsigned ru = x.u + 0x7fffu + ((x.u >> 16) & 1u);
    unsigned rv = y.u + 0x7fffu + ((y.u >> 16) & 1u);
    return (ru >> 16) | (rv & 0xffff0000u);
}

__device__ __forceinline__ void glds16(const void* g, void* l) {
    __builtin_amdgcn_global_load_lds(
        (const __attribute__((address_space(1))) void*)g,
        (__attribute__((address_space(3))) void*)l, 16, 0, 0);
}

// ---------------- K0a: vQp[b][k] = vQ[b]·Wq[:,k] + bq[k] ----------------
__global__ __launch_bounds__(256) void vqp_kernel(const float* __restrict__ vQ,
        const float* __restrict__ Wq, const float* __restrict__ bq,
        float* __restrict__ vQp)
{
    const int b = blockIdx.x, tid = threadIdx.x;
    __shared__ float sq[CD];
    sq[tid]       = vQ[b * CD + tid];
    sq[tid + 256] = vQ[b * CD + tid + 256];
    __syncthreads();
    float acc = bq[tid];
    #pragma unroll 8
    for (int d = 0; d < CD; ++d) acc += sq[d] * Wq[d * CK + tid];
    vQp[b * CK + tid] = acc;
}

// ---------------- K0b: WiT[k][d] = bf16(Wi[d][k]) (k-major, linear) ----------------
__global__ __launch_bounds__(256) void wit_kernel(const float* __restrict__ Wi,
        unsigned short* __restrict__ WiT)
{
    const int k = blockIdx.x, tid = threadIdx.x;
    for (int d = tid; d < CD; d += 256) {
        union { float f; unsigned u; } x; x.f = Wi[(size_t)d * CK + k];
        unsigned r = x.u + 0x7fffu + ((x.u >> 16) & 1u);
        WiT[(size_t)k * CD + d] = (unsigned short)(r >> 16);
    }
}

// ---------------- K1: fused scores + softmax pieces + num, single vI pass ----------
// BM=64 rows/block; A fully LDS-resident (64x520 bf16); B double-buffered glds.
// grid (32, 32).
__global__ __launch_bounds__(256, 1) void scores_fused_kernel(
        const float* __restrict__ vI, const unsigned short* __restrict__ WiT,
        const float* __restrict__ vQp, const float* __restrict__ Wp,
        float* __restrict__ numP, float* __restrict__ Zp, float* __restrict__ mP)
{
    constexpr int BM = 64, LDA = CD + 8;                     // A row: 520 ushorts
    __shared__ __align__(16) unsigned short sA[BM][LDA];     // 66,560 B (resident)
    __shared__ __align__(16) unsigned short sB[2][CK * 64];  // 2 x 32 KB dbuf
    float* sred = (float*)&sB[0][0];          // [4][64]
    float* sS   = ((float*)&sB[0][0]) + 256;  // [64] scores
    float* sW   = ((float*)&sB[0][0]) + 320;  // [64] exp weights
    float* sacc = ((float*)&sB[0][0]) + 512;  // [4][512] num partials

    const int tid  = threadIdx.x;
    const int b    = blockIdx.y;
    const int n0   = blockIdx.x * BM;
    const int wave = tid >> 6;
    const int lane = tid & 63;
    const int col  = lane & 15;
    const int quad = lane >> 4;
    const float* vIb = vI + ((size_t)b * CN + n0) * CD;

    // B glds source offsets (xor-swizzled col-groups): instr t covers 8 rows
    int gBoff[8];
    #pragma unroll
    for (int t = 0; t < 8; ++t) {
        int row = wave * 64 + t * 8 + (lane >> 3);
        int c   = (lane & 7) ^ (row & 7);
        gBoff[t] = row * CD + c * 8;    // ushort index; +d0 per chunk
    }
    const int ldsSlot = (wave * 8) * 512 + lane * 8;   // base within a buf (+t*512)

    // prefetch B chunk 0 (overlaps the A stage below)
    #pragma unroll
    for (int t = 0; t < 8; ++t)
        glds16(WiT + gBoff[t], &sB[0][ldsSlot + t * 512]);

    // stage ALL of A: 64x512 f32 -> bf16 LDS (coalesced float4, 32/thread)
    #pragma unroll
    for (int i = 0; i < 32; ++i) {
        int f  = i * 256 + tid;          // float4 index over 64x128
        int r  = f >> 7;
        int c4 = f & 127;
        float4 v = *reinterpret_cast<const float4*>(vIb + (size_t)r * CD + c4 * 4);
        uint2 p; p.x = pk2bf(v.x, v.y); p.y = pk2bf(v.z, v.w);
        *reinterpret_cast<uint2*>(&sA[r][c4 * 4]) = p;
    }

    f32x4 acc[4][4];
    #pragma unroll
    for (int mt = 0; mt < 4; ++mt)
        #pragma unroll
        for (int kt = 0; kt < 4; ++kt)
            acc[mt][kt] = (f32x4){0.f, 0.f, 0.f, 0.f};

    __syncthreads();   // A staged + B chunk0 landed

    for (int ch = 0; ch < 8; ++ch) {
        const unsigned short* bbuf = &sB[ch & 1][0];
        if (ch < 7) {   // prefetch next B chunk into the other buffer
            const int d0n = (ch + 1) * 64;
            unsigned short* nbuf = &sB[(ch + 1) & 1][0];
            #pragma unroll
            for (int t = 0; t < 8; ++t)
                glds16(WiT + gBoff[t] + d0n, nbuf + ldsSlot + t * 512);
        }
        #pragma unroll
        for (int s = 0; s < 2; ++s) {
            const int dk   = ch * 64 + s * 32 + quad * 8;
            const int slot = (4 * s + quad) ^ (col & 7);
            bf16x8 af[4], bfr[4];
            #pragma unroll
            for (int mt = 0; mt < 4; ++mt)
                af[mt] = *reinterpret_cast<const bf16x8*>(&sA[mt * 16 + col][dk]);
            #pragma unroll
            for (int kt = 0; kt < 4; ++kt) {
                int R = wave * 64 + kt * 16 + col;
                bfr[kt] = *reinterpret_cast<const bf16x8*>(bbuf + R * 64 + slot * 8);
            }
            #pragma unroll
            for (int mt = 0; mt < 4; ++mt)
                #pragma unroll
                for (int kt = 0; kt < 4; ++kt)
                    acc[mt][kt] = __builtin_amdgcn_mfma_f32_16x16x32_bf16(
                        af[mt], bfr[kt], acc[mt][kt], 0, 0, 0);
        }
        __syncthreads();   // drains prefetch (issued ~full compute phase ago)
    }

    // ---- epilogue 1: per-row scores ----
    float vq[4], wp[4];
    #pragma unroll
    for (int kt = 0; kt < 4; ++kt) {
        int k = wave * 64 + kt * 16 + col;
        vq[kt] = vQp[b * CK + k];
        wp[kt] = Wp[k];
    }
    float sp[4][4];
    #pragma unroll
    for (int mt = 0; mt < 4; ++mt)
        #pragma unroll
        for (int r = 0; r < 4; ++r) {
            float s = 0.f;
            #pragma unroll
            for (int kt = 0; kt < 4; ++kt) {
                float v = acc[mt][kt][r] + vq[kt];
                v = v > 0.f ? v : 0.01f * v;     // leaky relu
                s += v * wp[kt];
            }
            sp[mt][r] = s;
        }
    #pragma unroll
    for (int off = 1; off < 16; off <<= 1)
        #pragma unroll
        for (int mt = 0; mt < 4; ++mt)
            #pragma unroll
            for (int r = 0; r < 4; ++r)
                sp[mt][r] += __shfl_xor(sp[mt][r], off);
    // sB free after final K-loop barrier -> alias as scratch
    if (col == 0) {
        #pragma unroll
        for (int mt = 0; mt < 4; ++mt)
            #pragma unroll
            for (int r = 0; r < 4; ++r)
                sred[wave * 64 + mt * 16 + quad * 4 + r] = sp[mt][r];
    }
    __syncthreads();
    if (tid < BM)
        sS[tid] = sred[tid] + sred[64 + tid] + sred[128 + tid] + sred[192 + tid];
    __syncthreads();

    // ---- epilogue 2: block-local softmax pieces ----
    float m = -1e30f;
    #pragma unroll 8
    for (int i = 0; i < BM; ++i) m = fmaxf(m, sS[i]);
    if (tid < BM) sW[tid] = __expf(sS[tid] - m);
    __syncthreads();
    const int pidx = b * 32 + blockIdx.x;
    if (tid < 64) {
        float z = sW[tid];
        #pragma unroll
        for (int off = 32; off > 0; off >>= 1) z += __shfl_xor(z, off);
        if (tid == 0) { Zp[pidx] = z; mP[pidx] = m; }
    }

    // ---- epilogue 3: num[d] = sum_n w_n * A_lds[n][d]  (no global re-read) ----
    float a8[8] = {0.f, 0.f, 0.f, 0.f, 0.f, 0.f, 0.f, 0.f};
    #pragma unroll
    for (int i = 0; i < 16; ++i) {
        int n = wave * 16 + i;
        float w = sW[n];
        uint4 q = *reinterpret_cast<const uint4*>(&sA[n][lane * 8]);
        a8[0] += w * __uint_as_float(q.x << 16);
        a8[1] += w * __uint_as_float(q.x & 0xffff0000u);
        a8[2] += w * __uint_as_float(q.y << 16);
        a8[3] += w * __uint_as_float(q.y & 0xffff0000u);
        a8[4] += w * __uint_as_float(q.z << 16);
        a8[5] += w * __uint_as_float(q.z & 0xffff0000u);
        a8[6] += w * __uint_as_float(q.w << 16);
        a8[7] += w * __uint_as_float(q.w & 0xffff0000u);
    }
    *reinterpret_cast<float4*>(&sacc[wave * 512 + lane * 8])     = (float4){a8[0], a8[1], a8[2], a8[3]};
    *reinterpret_cast<float4*>(&sacc[wave * 512 + lane * 8 + 4]) = (float4){a8[4], a8[5], a8[6], a8[7]};
    __syncthreads();
    #pragma unroll
    for (int c = tid; c < CD; c += 256)
        numP[(size_t)pidx * CD + c] =
            sacc[c] + sacc[512 + c] + sacc[1024 + c] + sacc[1536 + c];
}

// ---------------- K2: combine 32 partials -> vbar; out = vbar@Wi + vQp ----------------
__global__ __launch_bounds__(256) void finalize_kernel(
        const float* __restrict__ numP, const float* __restrict__ Zp,
        const float* __restrict__ mP, const float* __restrict__ Wi,
        const float* __restrict__ vQp, float* __restrict__ out)
{
    const int b = blockIdx.x, tid = threadIdx.x;
    __shared__ float sv[CD];
    float M = -1e30f;
    #pragma unroll
    for (int j = 0; j < 32; ++j) M = fmaxf(M, mP[b * 32 + j]);
    float w[32]; float Zt = 0.f;
    #pragma unroll
    for (int j = 0; j < 32; ++j) {
        w[j] = __expf(mP[b * 32 + j] - M);
        Zt += w[j] * Zp[b * 32 + j];
    }
    const float inv = 1.f / Zt;
    for (int c = tid; c < CD; c += 256) {
        float s = 0.f;
        #pragma unroll
        for (int j = 0; j < 32; ++j) s += w[j] * numP[(size_t)(b * 32 + j) * CD + c];
        sv[c] = s * inv;
    }
    __syncthreads();
    float acc = vQp[b * CK + tid];
    #pragma unroll 8
    for (int d = 0; d < CD; ++d) acc += sv[d] * Wi[d * CK + tid];
    out[b * CK + tid] = acc;
}

extern "C" void kernel_launch(void* const* d_in, const int* in_sizes, int n_in,
                              void* d_out, int out_size, void* d_ws, size_t ws_size,
                              hipStream_t stream)
{
    const float* vI = (const float*)d_in[0];   // [B,N,D]
    const float* vQ = (const float*)d_in[1];   // [B,D]
    const float* Wi = (const float*)d_in[2];   // [D,K]
    const float* Wq = (const float*)d_in[3];   // [D,K]
    const float* bq = (const float*)d_in[4];   // [K]
    const float* Wp = (const float*)d_in[5];   // [K,1]
    // d_in[6] = bp: softmax-invariant, unused
    float* out = (float*)d_out;                // [B,K]

    char* ws = (char*)d_ws;
    float*          vQp  = (float*)(ws);                         //  32 KB
    unsigned short* WiT  = (unsigned short*)(ws + 32768);        // 256 KB
    float*          numP = (float*)(ws + 294912);                //   2 MB (1024x512)
    float*          Zp   = (float*)(ws + 294912 + 2097152);      //   4 KB
    float*          mP   = (float*)(ws + 294912 + 2097152 + 4096);

    vqp_kernel         <<<CB, 256, 0, stream>>>(vQ, Wq, bq, vQp);
    wit_kernel         <<<CK, 256, 0, stream>>>(Wi, WiT);
    scores_fused_kernel<<<dim3(CN / 64, CB), 256, 0, stream>>>(vI, WiT, vQp, Wp,
                                                               numP, Zp, mP);
    finalize_kernel    <<<CB, 256, 0, stream>>>(numP, Zp, mP, Wi, vQp, out);
}